// Round 21
// baseline (216.564 us; speedup 1.0000x reference)
//
#include <hip/hip_runtime.h>
#include <hip/hip_bf16.h>
#include <math.h>

#define T_TOK   2048
#define NHEADS  16
#define EPS_    1e-6f
#define THETA_  10000.0f

typedef __attribute__((ext_vector_type(8))) short short8v;
typedef __attribute__((ext_vector_type(4))) float f32x4;

__device__ inline unsigned short f2bf(float f) {
    union { float f; unsigned u; } v; v.f = f;
    unsigned r = v.u + 0x7fffu + ((v.u >> 16) & 1u);
    return (unsigned short)(r >> 16);
}
__device__ inline float bf2f(unsigned short b) {
    return __uint_as_float(((unsigned)b) << 16);
}

// async global->LDS, 16B per lane; LDS dest is wave-uniform base + lane*16
__device__ __forceinline__ void gload16(const unsigned short* src, unsigned short* lds) {
    __builtin_amdgcn_global_load_lds(
        (const __attribute__((address_space(1))) unsigned int*)src,
        (__attribute__((address_space(3))) unsigned int*)lds, 16, 0, 0);
}

// ---------------- block-wide reduce (256 threads = 4 waves) ----------------
__device__ inline float block_reduce(float v, bool is_max, float* sred) {
    #pragma unroll
    for (int off = 32; off > 0; off >>= 1) {
        float o = __shfl_down(v, off, 64);
        v = is_max ? fmaxf(v, o) : (v + o);
    }
    int tid = threadIdx.x;
    __syncthreads();
    if ((tid & 63) == 0) sred[tid >> 6] = v;
    __syncthreads();
    float r = sred[0];
    #pragma unroll
    for (int w = 1; w < 4; ++w) r = is_max ? fmaxf(r, sred[w]) : (r + sred[w]);
    return r;
}

// ---------------- fp32 -> bf16 elementwise (n4 = n/4) ----------------
__global__ __launch_bounds__(256) void conv_bf16(const float* __restrict__ in,
    unsigned short* __restrict__ out, int n4)
{
    int i = blockIdx.x * 256 + threadIdx.x;
    if (i >= n4) return;
    float4 v = ((const float4*)in)[i];
    ushort4 o;
    o.x = f2bf(v.x); o.y = f2bf(v.y); o.z = f2bf(v.z); o.w = f2bf(v.w);
    ((ushort4*)out)[i] = o;
}

// ------------- fp32 [R][C] -> bf16 transposed [C][R] -------------
__global__ __launch_bounds__(256) void wt_bf16(const float* __restrict__ W,
    unsigned short* __restrict__ Wt, int R, int C)
{
    __shared__ float tile[32][33];
    int c0 = blockIdx.x * 32, r0 = blockIdx.y * 32;
    int tx = threadIdx.x & 31, ty = threadIdx.x >> 5;  // ty 0..7
    #pragma unroll
    for (int i = 0; i < 4; ++i)
        tile[ty + i * 8][tx] = W[(size_t)(r0 + ty + i * 8) * C + c0 + tx];
    __syncthreads();
    #pragma unroll
    for (int i = 0; i < 4; ++i)
        Wt[(size_t)(c0 + ty + i * 8) * R + r0 + tx] = f2bf(tile[tx][ty + i * 8]);
}

// ===== bf16 MFMA GEMM: 128x64 tile, BK=64, 4 waves; 1D grid + XCD-chunked remap =====
// M fixed at 2048 -> 16 row-tiles (by = T & 15, bx = T >> 4).
#define STAGE_GEMM64(buf, k0)                                                 \
    {   _Pragma("unroll")                                                     \
        for (int p = 0; p < 4; ++p) {                                         \
            int u = p * 256 + tid;                                            \
            int r = u >> 3, cu = u & 7;                                       \
            gload16(A + (size_t)(r0 + r) * K + (k0) + ((cu ^ (r & 7)) << 3),  \
                    As[buf] + (p * 256 + wid * 64) * 8);                      \
        }                                                                     \
        _Pragma("unroll")                                                     \
        for (int p = 0; p < 2; ++p) {                                         \
            int u = p * 256 + tid;                                            \
            int r = u >> 3, cu = u & 7;                                       \
            gload16(Bt + (size_t)(c0 + r) * K + (k0) + ((cu ^ (r & 7)) << 3), \
                    Bs[buf] + (p * 256 + wid * 64) * 8);                      \
        }                                                                     \
    }

#define GEMM_BODY64()                                                         \
    STAGE_GEMM64(0, 0)                                                        \
    const int nkt = K >> 6;                                                   \
    int buf = 0;                                                              \
    for (int kt = 0; kt < nkt; ++kt) {                                        \
        if (kt + 1 < nkt) {                                                   \
            STAGE_GEMM64(buf ^ 1, (kt + 1) << 6)                              \
            asm volatile("s_waitcnt vmcnt(6)" ::: "memory");                  \
        } else {                                                              \
            asm volatile("s_waitcnt vmcnt(0)" ::: "memory");                  \
        }                                                                     \
        __builtin_amdgcn_s_barrier();                                         \
        _Pragma("unroll")                                                     \
        for (int ks = 0; ks < 2; ++ks) {                                      \
            short8v af[4], bf[2];                                             \
            _Pragma("unroll")                                                 \
            for (int m = 0; m < 4; ++m) {                                     \
                int row = wr * 64 + m * 16 + lrow;                            \
                af[m] = *(const short8v*)((char*)As[buf] + row * 128 +        \
                        (((ks * 4 + lkg) ^ (row & 7)) << 4));                 \
            }                                                                 \
            _Pragma("unroll")                                                 \
            for (int n = 0; n < 2; ++n) {                                     \
                int row = wc * 32 + n * 16 + lrow;                            \
                bf[n] = *(const short8v*)((char*)Bs[buf] + row * 128 +        \
                        (((ks * 4 + lkg) ^ (row & 7)) << 4));                 \
            }                                                                 \
            _Pragma("unroll")                                                 \
            for (int m = 0; m < 4; ++m)                                       \
                _Pragma("unroll")                                             \
                for (int n = 0; n < 2; ++n)                                   \
                    acc[m][n] = __builtin_amdgcn_mfma_f32_16x16x32_bf16(      \
                        af[m], bf[n], acc[m][n], 0, 0, 0);                    \
        }                                                                     \
        __builtin_amdgcn_s_barrier();                                         \
        buf ^= 1;                                                             \
    }

// bijective XCD-chunk remap (nwg % 8 == 0): each XCD owns a contiguous T-range
#define XCD_REMAP()                                                           \
    const int nwg = gridDim.x;                                                \
    const int L = blockIdx.x;                                                 \
    const int T = (L & 7) * (nwg >> 3) + (L >> 3);                            \
    const int r0 = (T & 15) * 128, c0 = (T >> 4) * 64;

template<bool BF16OUT>
__global__ __launch_bounds__(256) void gemm_bf16(
    const unsigned short* __restrict__ A,   // [2048][K] bf16
    const unsigned short* __restrict__ Bt,  // [>=nx*64][K] bf16
    void* __restrict__ Cv, int N, int K, int ldc, float oscale)
{
    __shared__ __align__(16) unsigned short As[2][128 * 64];
    __shared__ __align__(16) unsigned short Bs[2][64 * 64];
    const int tid = threadIdx.x;
    const int lane = tid & 63, wid = tid >> 6;
    const int wr = wid >> 1, wc = wid & 1;
    const int lrow = lane & 15, lkg = lane >> 4;
    XCD_REMAP()

    f32x4 acc[4][2];
    #pragma unroll
    for (int m = 0; m < 4; ++m)
        #pragma unroll
        for (int n = 0; n < 2; ++n) acc[m][n] = (f32x4)0.f;

    GEMM_BODY64()

    // D layout: col = lane&15, row = (lane>>4)*4 + j
    #pragma unroll
    for (int m = 0; m < 4; ++m) {
        int grow = r0 + wr * 64 + m * 16 + lkg * 4;
        #pragma unroll
        for (int n = 0; n < 2; ++n) {
            int gcol = c0 + wc * 32 + n * 16 + lrow;
            if (gcol < N) {
                #pragma unroll
                for (int j = 0; j < 4; ++j) {
                    float v = acc[m][n][j] * oscale;
                    if (BF16OUT)
                        ((unsigned short*)Cv)[(size_t)(grow + j) * ldc + gcol] = f2bf(v);
                    else
                        ((float*)Cv)[(size_t)(grow + j) * ldc + gcol] = v;
                }
            }
        }
    }
}

// ==== G4 special: kvb GEMM (N=4096, K=512) writing Kc / Vtc caches directly ====
__global__ __launch_bounds__(256) void gemm_kv(
    const unsigned short* __restrict__ A,   // kv_cb [2048][512]
    const unsigned short* __restrict__ Bt,  // wbuf  [4096][512]
    unsigned short* __restrict__ Kc,        // [16][2048][192]
    unsigned short* __restrict__ Vtc)       // [16][128][2048]
{
    __shared__ __align__(16) unsigned short As[2][128 * 64];
    __shared__ __align__(16) unsigned short Bs[2][64 * 64];
    const int tid = threadIdx.x;
    const int lane = tid & 63, wid = tid >> 6;
    const int wr = wid >> 1, wc = wid & 1;
    const int lrow = lane & 15, lkg = lane >> 4;
    const int K = 512;
    XCD_REMAP()

    f32x4 acc[4][2];
    #pragma unroll
    for (int m = 0; m < 4; ++m)
        #pragma unroll
        for (int n = 0; n < 2; ++n) acc[m][n] = (f32x4)0.f;

    GEMM_BODY64()

    #pragma unroll
    for (int m = 0; m < 4; ++m) {
        int grow = r0 + wr * 64 + m * 16 + lkg * 4;   // t base (mult of 4)
        #pragma unroll
        for (int n = 0; n < 2; ++n) {
            int gcol = c0 + wc * 32 + n * 16 + lrow;
            int head = gcol >> 8, c = gcol & 255;
            if (c < 128) {
                #pragma unroll
                for (int j = 0; j < 4; ++j)
                    Kc[((size_t)head * 2048 + grow + j) * 192 + c] = f2bf(acc[m][n][j]);
            } else {
                ushort4 o;
                o.x = f2bf(acc[m][n][0]); o.y = f2bf(acc[m][n][1]);
                o.z = f2bf(acc[m][n][2]); o.w = f2bf(acc[m][n][3]);
                *(ushort4*)(Vtc + ((size_t)head * 128 + (c - 128)) * 2048 + grow) = o;
            }
        }
    }
}

// ---- fused row kernel on qkv_c [2048][2112] ----
__global__ __launch_bounds__(256) void rms_kv(const float* __restrict__ qkv,
    const float* __restrict__ gq, const float* __restrict__ gkv,
    const int* __restrict__ positions, unsigned short* __restrict__ q_cb,
    unsigned short* __restrict__ kv_cb, float* __restrict__ kpe)
{
    __shared__ float sred[4];
    int row = blockIdx.x, tid = threadIdx.x;
    const float* p = qkv + (size_t)row * 2112;

    float ss = 0.f;
    for (int i = tid; i < 1536; i += 256) { float v = p[i]; ss += v * v; }
    ss = block_reduce(ss, false, sred);
    float sc = rsqrtf(ss / 1536.0f + EPS_);
    for (int i = tid; i < 1536; i += 256)
        q_cb[(size_t)row * 1536 + i] = f2bf(p[i] * sc * gq[i]);

    float s2 = 0.f;
    for (int i = tid; i < 512; i += 256) { float v = p[1536 + i]; s2 += v * v; }
    s2 = block_reduce(s2, false, sred);
    float sc2 = rsqrtf(s2 / 512.0f + EPS_);
    for (int i = tid; i < 512; i += 256)
        kv_cb[(size_t)row * 512 + i] = f2bf(p[1536 + i] * sc2 * gkv[i]);

    if (tid < 32) {
        int i = tid;
        float pos = (float)positions[row];
        float inv = powf(THETA_, -(float)i / 32.0f);
        float ang = pos * inv;
        float c = cosf(ang), s = sinf(ang);
        float x1 = p[2048 + i], x2 = p[2080 + i];
        kpe[(size_t)row * 64 + i]      = x1 * c - x2 * s;
        kpe[(size_t)row * 64 + 32 + i] = x2 * c + x1 * s;
    }
}

// ---- broadcast roped k_pe into all 16 heads' Kc[..][128:192] ----
__global__ __launch_bounds__(256) void kpe_kc(const float* __restrict__ kpe,
    unsigned short* __restrict__ Kc)
{
    int t = blockIdx.x, tid = threadIdx.x;
    int n = tid >> 4, i4 = (tid & 15) * 4;
    float4 p = *(const float4*)(kpe + (size_t)t * 64 + i4);
    ushort4 o; o.x = f2bf(p.x); o.y = f2bf(p.y); o.z = f2bf(p.z); o.w = f2bf(p.w);
    *(ushort4*)(Kc + ((size_t)n * 2048 + t) * 192 + 128 + i4) = o;
}

// ---- in-place RoPE fixup on qb bf16 (cols 128..191 per head); scale already in ----
__global__ __launch_bounds__(256) void rope_fix(unsigned short* __restrict__ qb,
    const int* __restrict__ positions)
{
    int t = blockIdx.x, tid = threadIdx.x;
    int n = tid >> 4;                 // head 0..15
    int i0 = (tid & 15) * 2;          // pair base 0..30
    float pos = (float)positions[t];
    unsigned short* p = qb + ((size_t)t * 16 + n) * 192 + 128;
    #pragma unroll
    for (int e = 0; e < 2; ++e) {
        int i = i0 + e;
        float inv = powf(THETA_, -(float)i / 32.0f);
        float ang = pos * inv;
        float c = cosf(ang), s = sinf(ang);
        float x1 = bf2f(p[i]), x2 = bf2f(p[32 + i]);
        p[i]      = f2bf(x1 * c - x2 * s);
        p[32 + i] = f2bf(x2 * c + x1 * s);
    }
}

// ==== MFMA flash attention, NCH=4 KV-split, swapped-QK^T, exp2 domain ====
#define QBLK  64
#define KVBLK 64
#define NCH   4

__global__ __launch_bounds__(256) void attn_part(
    const unsigned short* __restrict__ qb,    // [T][16][192] bf16 (scale*log2e folded)
    const unsigned short* __restrict__ Kc,    // [16][T][192] bf16
    const unsigned short* __restrict__ Vtc,   // [16][128][T] bf16
    unsigned short* __restrict__ Opart,       // [2048][64][128] bf16 unnormalized
    float2* __restrict__ Ml)                  // [2048][64] (m, l) — m in log2 units
{
    __shared__ __align__(16) unsigned short Ks[KVBLK * 192];   // 24 KB
    __shared__ __align__(16) unsigned short Vt[128 * KVBLK];   // 16 KB
    __shared__ __align__(16) unsigned short Ps[4][16 * KVBLK]; //  8 KB (48 total)

    const int bid = blockIdx.x;               // 0..2047
    const int xcd = bid & 7;
    const int j   = bid >> 3;                 // 0..255
    const int n   = xcd * 2 + (j >= 128);
    const int jj  = (j >= 128) ? j - 128 : j; // 0..127
    const int qt  = 31 - (jj >> 2);
    const int ch  = jj & 3;

    const int nt  = qt + 1;
    const int csz = (nt + NCH - 1) / NCH;
    const int tstart = ch * csz;
    if (tstart >= nt) return;
    const int tend = min(tstart + csz, nt);

    const int tid = threadIdx.x;
    const int lane = tid & 63, wid = tid >> 6;
    const int lrow = lane & 15;
    const int lkg  = lane >> 4;
    const int q0 = qt * QBLK;
    const int qrow_g = q0 + wid * 16 + lrow;
    const int pidx = ((n * 32 + qt) * NCH + ch);

    const unsigned short* Kh = Kc  + (size_t)n * 2048 * 192;
    const unsigned short* Vh = Vtc + (size_t)n * 128 * 2048;

    int koff[6], voff[4];
    #pragma unroll
    for (int p = 0; p < 6; ++p) {
        int u = p * 256 + tid;
        int row = u / 24, c8 = u % 24;
        koff[p] = row * 192 + ((c8 ^ (row & 7)) << 3);
    }
    #pragma unroll
    for (int p = 0; p < 4; ++p) {
        int u = p * 256 + tid;
        int dv = u >> 3, c8 = u & 7;
        voff[p] = dv * 2048 + ((c8 ^ (dv & 7)) << 3);
    }

    short8v qf[6];
    {
        const unsigned short* qrow = qb + ((size_t)qrow_g * 16 + n) * 192;
        #pragma unroll
        for (int ds = 0; ds < 6; ++ds)
            qf[ds] = *(const short8v*)(qrow + ds * 32 + lkg * 8);
    }

    f32x4 oacc[8];
    #pragma unroll
    for (int i = 0; i < 8; ++i) oacc[i] = (f32x4)0.f;
    float mrow = -3e38f;
    float lsum = 0.f;

    #pragma unroll
    for (int p = 0; p < 6; ++p)
        gload16(Kh + (size_t)tstart * KVBLK * 192 + koff[p], Ks + (p * 256 + wid * 64) * 8);
    #pragma unroll
    for (int p = 0; p < 4; ++p)
        gload16(Vh + tstart * KVBLK + voff[p], Vt + (p * 256 + wid * 64) * 8);

    for (int tile = tstart; tile < tend; ++tile) {
        const int s0 = tile * KVBLK;
        const bool more = (tile + 1 < tend);

        asm volatile("s_waitcnt vmcnt(4)" ::: "memory");   // K[t] landed
        __builtin_amdgcn_s_barrier();

        f32x4 sacc[4];
        #pragma unroll
        for (int ct = 0; ct < 4; ++ct) sacc[ct] = (f32x4)0.f;
        __builtin_amdgcn_s_setprio(1);
        #pragma unroll
        for (int ds = 0; ds < 6; ++ds) {
            #pragma unroll
            for (int ct = 0; ct < 4; ++ct) {
                int krow = ct * 16 + lrow;
                int byte = (krow * 384 + ds * 64 + lkg * 16) ^ ((krow & 7) << 4);
                short8v kf = *(const short8v*)((char*)Ks + byte);
                sacc[ct] = __builtin_amdgcn_mfma_f32_16x16x32_bf16(kf, qf[ds], sacc[ct], 0, 0, 0);
            }
        }
        __builtin_amdgcn_s_setprio(0);

        #pragma unroll
        for (int ct = 0; ct < 4; ++ct) {
            #pragma unroll
            for (int jq = 0; jq < 4; ++jq) {
                int key = s0 + ct * 16 + lkg * 4 + jq;
                if (key > qrow_g) sacc[ct][jq] = -3e38f;
            }
        }

        // ---- in-lane softmax (log2 domain) ----
        float tm = -3e38f;
        #pragma unroll
        for (int ct = 0; ct < 4; ++ct) {
            float a = fmaxf(sacc[ct][0], sacc[ct][1]);
            float b = fmaxf(sacc[ct][2], sacc[ct][3]);
            tm = fmaxf(tm, fmaxf(a, b));
        }
        tm = fmaxf(tm, __shfl_xor(tm, 16, 64));
        tm = fmaxf(tm, __shfl_xor(tm, 32, 64));

        const bool grow = !__all(tm <= mrow);   // defer-max
        float corr = 1.f;
        if (grow) {
            float mn = fmaxf(mrow, tm);
            corr = exp2f(mrow - mn);
            mrow = mn;
        }

        float psum = 0.f;
        unsigned short pb[4][4];
        #pragma unroll
        for (int ct = 0; ct < 4; ++ct)
            #pragma unroll
            for (int jq = 0; jq < 4; ++jq) {
                float sv = sacc[ct][jq];
                float p = (sv > -1e37f) ? exp2f(sv - mrow) : 0.f;
                psum += p;
                pb[ct][jq] = f2bf(p);
            }
        psum += __shfl_xor(psum, 16, 64);
        psum += __shfl_xor(psum, 32, 64);
        lsum = grow ? (lsum * corr + psum) : (lsum + psum);

        if (grow) {
            float corr4[4];
            #pragma unroll
            for (int jq = 0; jq < 4; ++jq)
                corr4[jq] = __shfl(corr, (lane & 48) | (lkg * 4 + jq), 64);
            #pragma unroll
            for (int dt = 0; dt < 8; ++dt)
                #pragma unroll
                for (int jq = 0; jq < 4; ++jq) oacc[dt][jq] *= corr4[jq];
        }

        #pragma unroll
        for (int ct = 0; ct < 4; ++ct) {
            int c0k = ct * 16 + lkg * 4;
            int byte = ((lrow * 64 + c0k) * 2) ^ ((lrow & 7) << 4);
            uint2 w;
            w.x = (unsigned)pb[ct][0] | ((unsigned)pb[ct][1] << 16);
            w.y = (unsigned)pb[ct][2] | ((unsigned)pb[ct][3] << 16);
            *(uint2*)((char*)Ps[wid] + byte) = w;
        }

        asm volatile("s_waitcnt vmcnt(0)" ::: "memory");   // V[t] landed
        __builtin_amdgcn_s_barrier();

        __builtin_amdgcn_s_setprio(1);
        #pragma unroll
        for (int ks = 0; ks < 2; ++ks) {
            int abyte = ((lrow * 64 + ks * 32 + lkg * 8) * 2) ^ ((lrow & 7) << 4);
            short8v af = *(const short8v*)((char*)Ps[wid] + abyte);
            #pragma unroll
            for (int dt = 0; dt < 8; ++dt) {
                int vrow = dt * 16 + lrow;
                int byte = ((vrow * 128 + ks * 64 + lkg * 16)) ^ ((vrow & 7) << 4);
                short8v bf = *(const short8v*)((char*)Vt + byte);
                oacc[dt] = __builtin_amdgcn_mfma_f32_16x16x32_bf16(af, bf, oacc[dt], 0, 0, 0);
            }
        }
        __builtin_amdgcn_s_setprio(0);

        __builtin_amdgcn_s_barrier();
        if (more) {
            const int s1 = s0 + KVBLK;
            #pragma unroll
            for (int p = 0; p < 6; ++p)
                gload16(Kh + (size_t)s1 * 192 + koff[p], Ks + (p * 256 + wid * 64) * 8);
            #pragma unroll
            for (int p = 0; p < 4; ++p)
                gload16(Vh + s1 + voff[p], Vt + (p * 256 + wid * 64) * 8);
        }
    }

    #pragma unroll
    for (int dt = 0; dt < 8; ++dt)
        #pragma unroll
        for (int jq = 0; jq < 4; ++jq) {
            int row = wid * 16 + lkg * 4 + jq;
            Opart[(size_t)pidx * 8192 + row * 128 + dt * 16 + lrow] = f2bf(oacc[dt][jq]);
        }
    if (lkg == 0)
        Ml[(size_t)pidx * 64 + wid * 16 + lrow] = make_float2(mrow, lsum);
}

// -------- combine <=4 partials per (head, qtile); weights in exp2 domain --------
__global__ __launch_bounds__(256) void attn_combine(
    const unsigned short* __restrict__ Opart, const float2* __restrict__ Ml,
    unsigned short* __restrict__ aob)
{
    const int bid = blockIdx.x;               // 512 = head*32 + qt
    const int head = bid >> 5, qt = bid & 31;
    const int nt = qt + 1, csz = (nt + NCH - 1) / NCH;
    const int nch = (nt + csz - 1) / csz;
    const int tid = threadIdx.x;
    const int r = tid >> 2, qc = tid & 3;
    const int base = (head * 32 + qt) * NCH;

    float mi[NCH], li[NCH];
    float m = -3e38f;
    #pragma unroll
    for (int i = 0; i < NCH; ++i) {
        mi[i] = -3e38f; li[i] = 0.f;
        if (i < nch) {
            float2 v = Ml[(size_t)(base + i) * 64 + r];
            mi[i] = v.x; li[i] = v.y;
            m = fmaxf(m, v.x);
        }
    }
    float acc[32];
    #pragma unroll
    for (int u = 0; u < 32; ++u) acc[u] = 0.f;
    float l = 0.f;
    #pragma unroll
    for (int i = 0; i < NCH; ++i) {
        if (i < nch) {
            float w = exp2f(mi[i] - m);
            l += w * li[i];
            const unsigned short* op = Opart + (size_t)(base + i) * 8192 + r * 128 + qc * 32;
            #pragma unroll
            for (int u = 0; u < 4; ++u) {
                short8v v8 = *(const short8v*)(op + u * 8);
                #pragma unroll
                for (int e = 0; e < 8; ++e)
                    acc[u * 8 + e] += w * bf2f((unsigned short)v8[e]);
            }
        }
    }
    float invl = 1.0f / l;
    unsigned short* dst = aob + (size_t)(qt * 64 + r) * 2048 + head * 128 + qc * 32;
    #pragma unroll
    for (int u = 0; u < 4; ++u) {
        short8v o8;
        #pragma unroll
        for (int e = 0; e < 8; ++e) o8[e] = (short)f2bf(acc[u * 8 + e] * invl);
        *(short8v*)(dst + u * 8) = o8;
    }
}

extern "C" void kernel_launch(void* const* d_in, const int* in_sizes, int n_in,
                              void* d_out, int out_size, void* d_ws, size_t ws_size,
                              hipStream_t stream)
{
    const float* x         = (const float*)d_in[0];
    const int*   positions = (const int*)  d_in[1];
    const float* w_q_a     = (const float*)d_in[2];
    const float* q_a_norm  = (const float*)d_in[3];
    const float* w_q_b     = (const float*)d_in[4];
    const float* w_kv_a    = (const float*)d_in[5];
    const float* kv_a_norm = (const float*)d_in[6];
    const float* w_kv_b    = (const float*)d_in[7];
    const float* w_o       = (const float*)d_in[8];
    float* out = (float*)d_out;

    // softmax scale * log2(e), folded into G2's epilogue
    const float QSCALE = 0.07216878364870323f * 1.4426950408889634f;

    // ---- workspace layout (~77.6 MB) ----
    // D0 union (35.66 MB): [qkv_c fp32 | q_cb | kv_cb | kpe | wbuf] all dead
    // before attn_part; Opart (33.55 MB) + Ml (1.05 MB) alias the region.
    // G5's wt_bf16 refills wbuf only AFTER attn_combine (Opart/Ml dead).
    char* base = (char*)d_ws;
    char* D0 = base;
    float* qkv_c = (float*)D0;                                     // 2048*2112*4 = 17.30 MB
    unsigned short* q_cb  = (unsigned short*)(D0 + 17301504);      // 2048*1536*2 =  6.29 MB
    unsigned short* kv_cb = (unsigned short*)(D0 + 23592960);      // 2048*512*2  =  2.10 MB
    float* kpe            = (float*)(D0 + 25690112);               // 2048*64*4   =  0.52 MB
    unsigned short* wbuf  = (unsigned short*)(D0 + 26214400);      // up to 9.44 MB
    unsigned short* Opart = (unsigned short*)D0;                   // 2048*8192*2 = 33.55 MB
    float2* Ml            = (float2*)(D0 + 33554432);              // 2048*64*8   =  1.05 MB
    char* D1 = D0 + 35651584;
    unsigned short* Kc  = (unsigned short*)D1;                     // 16*2048*192 = 12.58 MB
    unsigned short* Vtc = Kc + (size_t)16 * 2048 * 192;            // 16*128*2048 =  8.39 MB
    char* D2 = D1 + (size_t)(12582912 + 8388608);
    unsigned short* xb  = (unsigned short*)D2;                     // 2048*2048*2 =  8.39 MB
    unsigned short* aob = xb;                                      // alias (xb dead after G13)
    char* D3 = D2 + 8388608;
    unsigned short* qb = (unsigned short*)D3;                      // 2048*16*192*2 = 12.58 MB

    dim3 blk(256);

    conv_bf16<<<(2048 * 2048 / 4 + 255) / 256, blk, 0, stream>>>(x, xb, 2048 * 2048 / 4);

    // G13: qkv_c = x @ [w_q_a | w_kv_a]  (N=2112, K=2048) fp32 out; 528 blocks
    wt_bf16<<<dim3(1536 / 32, 2048 / 32), blk, 0, stream>>>(w_q_a, wbuf, 2048, 1536);
    wt_bf16<<<dim3(576 / 32, 2048 / 32), blk, 0, stream>>>(w_kv_a, wbuf + (size_t)1536 * 2048, 2048, 576);
    gemm_bf16<false><<<528, blk, 0, stream>>>(xb, wbuf, qkv_c, 2112, 2048, 2112, 1.0f);
    rms_kv<<<2048, blk, 0, stream>>>(qkv_c, q_a_norm, kv_a_norm, positions, q_cb, kv_cb, kpe);

    // G2: qb = (q_cb @ w_q_b) * QSCALE, bf16 direct; 768 blocks
    wt_bf16<<<dim3(3072 / 32, 1536 / 32), blk, 0, stream>>>(w_q_b, wbuf, 1536, 3072);
    gemm_bf16<true><<<768, blk, 0, stream>>>(q_cb, wbuf, qb, 3072, 1536, 3072, QSCALE);
    rope_fix<<<2048, blk, 0, stream>>>(qb, positions);

    kpe_kc<<<2048, blk, 0, stream>>>(kpe, Kc);

    // G4: (kv_cb @ w_kv_b) -> Kc / Vtc directly; 1024 blocks
    wt_bf16<<<dim3(4096 / 32, 512 / 32), blk, 0, stream>>>(w_kv_b, wbuf, 512, 4096);
    gemm_kv<<<1024, blk, 0, stream>>>(kv_cb, wbuf, Kc, Vtc);

    // attention: 2048 NCH=4 KV-split jobs + combine
    attn_part<<<2048, blk, 0, stream>>>(qb, Kc, Vtc, Opart, Ml);
    attn_combine<<<512, blk, 0, stream>>>(Opart, Ml, aob);

    // G5: out = aob @ w_o   (N=2048, K=2048) fp32 out; 512 blocks
    wt_bf16<<<dim3(2048 / 32, 2048 / 32), blk, 0, stream>>>(w_o, wbuf, 2048, 2048);
    gemm_bf16<false><<<512, blk, 0, stream>>>(aob, wbuf, out, 2048, 2048, 2048, 1.0f);
}

// Round 22
// 210.813 us; speedup vs baseline: 1.0273x; 1.0273x over previous
//
#include <hip/hip_runtime.h>
#include <hip/hip_bf16.h>
#include <math.h>

#define T_TOK   2048
#define NHEADS  16
#define EPS_    1e-6f
#define THETA_  10000.0f

typedef __attribute__((ext_vector_type(8))) short short8v;
typedef __attribute__((ext_vector_type(4))) float f32x4;

__device__ inline unsigned short f2bf(float f) {
    union { float f; unsigned u; } v; v.f = f;
    unsigned r = v.u + 0x7fffu + ((v.u >> 16) & 1u);
    return (unsigned short)(r >> 16);
}
__device__ inline float bf2f(unsigned short b) {
    return __uint_as_float(((unsigned)b) << 16);
}

// async global->LDS, 16B per lane; LDS dest is wave-uniform base + lane*16
__device__ __forceinline__ void gload16(const unsigned short* src, unsigned short* lds) {
    __builtin_amdgcn_global_load_lds(
        (const __attribute__((address_space(1))) unsigned int*)src,
        (__attribute__((address_space(3))) unsigned int*)lds, 16, 0, 0);
}

// ---------------- block-wide reduce (256 threads = 4 waves) ----------------
__device__ inline float block_reduce(float v, bool is_max, float* sred) {
    #pragma unroll
    for (int off = 32; off > 0; off >>= 1) {
        float o = __shfl_down(v, off, 64);
        v = is_max ? fmaxf(v, o) : (v + o);
    }
    int tid = threadIdx.x;
    __syncthreads();
    if ((tid & 63) == 0) sred[tid >> 6] = v;
    __syncthreads();
    float r = sred[0];
    #pragma unroll
    for (int w = 1; w < 4; ++w) r = is_max ? fmaxf(r, sred[w]) : (r + sred[w]);
    return r;
}

// ---------------- fp32 -> bf16 elementwise (n4 = n/4) ----------------
__global__ __launch_bounds__(256) void conv_bf16(const float* __restrict__ in,
    unsigned short* __restrict__ out, int n4)
{
    int i = blockIdx.x * 256 + threadIdx.x;
    if (i >= n4) return;
    float4 v = ((const float4*)in)[i];
    ushort4 o;
    o.x = f2bf(v.x); o.y = f2bf(v.y); o.z = f2bf(v.z); o.w = f2bf(v.w);
    ((ushort4*)out)[i] = o;
}

// ------------- fp32 [R][C] -> bf16 transposed [C][R] -------------
__global__ __launch_bounds__(256) void wt_bf16(const float* __restrict__ W,
    unsigned short* __restrict__ Wt, int R, int C)
{
    __shared__ float tile[32][33];
    int c0 = blockIdx.x * 32, r0 = blockIdx.y * 32;
    int tx = threadIdx.x & 31, ty = threadIdx.x >> 5;  // ty 0..7
    #pragma unroll
    for (int i = 0; i < 4; ++i)
        tile[ty + i * 8][tx] = W[(size_t)(r0 + ty + i * 8) * C + c0 + tx];
    __syncthreads();
    #pragma unroll
    for (int i = 0; i < 4; ++i)
        Wt[(size_t)(c0 + ty + i * 8) * R + r0 + tx] = f2bf(tile[tx][ty + i * 8]);
}

// ===== bf16 MFMA GEMM: 128x64 tile, BK=64, 4 waves; 1D grid + XCD-chunked remap =====
#define STAGE_GEMM64(buf, k0)                                                 \
    {   _Pragma("unroll")                                                     \
        for (int p = 0; p < 4; ++p) {                                         \
            int u = p * 256 + tid;                                            \
            int r = u >> 3, cu = u & 7;                                       \
            gload16(A + (size_t)(r0 + r) * K + (k0) + ((cu ^ (r & 7)) << 3),  \
                    As[buf] + (p * 256 + wid * 64) * 8);                      \
        }                                                                     \
        _Pragma("unroll")                                                     \
        for (int p = 0; p < 2; ++p) {                                         \
            int u = p * 256 + tid;                                            \
            int r = u >> 3, cu = u & 7;                                       \
            gload16(Bt + (size_t)(c0 + r) * K + (k0) + ((cu ^ (r & 7)) << 3), \
                    Bs[buf] + (p * 256 + wid * 64) * 8);                      \
        }                                                                     \
    }

#define GEMM_BODY64()                                                         \
    STAGE_GEMM64(0, 0)                                                        \
    const int nkt = K >> 6;                                                   \
    int buf = 0;                                                              \
    for (int kt = 0; kt < nkt; ++kt) {                                        \
        if (kt + 1 < nkt) {                                                   \
            STAGE_GEMM64(buf ^ 1, (kt + 1) << 6)                              \
            asm volatile("s_waitcnt vmcnt(6)" ::: "memory");                  \
        } else {                                                              \
            asm volatile("s_waitcnt vmcnt(0)" ::: "memory");                  \
        }                                                                     \
        __builtin_amdgcn_s_barrier();                                         \
        _Pragma("unroll")                                                     \
        for (int ks = 0; ks < 2; ++ks) {                                      \
            short8v af[4], bf[2];                                             \
            _Pragma("unroll")                                                 \
            for (int m = 0; m < 4; ++m) {                                     \
                int row = wr * 64 + m * 16 + lrow;                            \
                af[m] = *(const short8v*)((char*)As[buf] + row * 128 +        \
                        (((ks * 4 + lkg) ^ (row & 7)) << 4));                 \
            }                                                                 \
            _Pragma("unroll")                                                 \
            for (int n = 0; n < 2; ++n) {                                     \
                int row = wc * 32 + n * 16 + lrow;                            \
                bf[n] = *(const short8v*)((char*)Bs[buf] + row * 128 +        \
                        (((ks * 4 + lkg) ^ (row & 7)) << 4));                 \
            }                                                                 \
            _Pragma("unroll")                                                 \
            for (int m = 0; m < 4; ++m)                                       \
                _Pragma("unroll")                                             \
                for (int n = 0; n < 2; ++n)                                   \
                    acc[m][n] = __builtin_amdgcn_mfma_f32_16x16x32_bf16(      \
                        af[m], bf[n], acc[m][n], 0, 0, 0);                    \
        }                                                                     \
        __builtin_amdgcn_s_barrier();                                         \
        buf ^= 1;                                                             \
    }

// bijective XCD-chunk remap (nwg % 8 == 0): each XCD owns a contiguous T-range
#define XCD_REMAP()                                                           \
    const int nwg = gridDim.x;                                                \
    const int L = blockIdx.x;                                                 \
    const int T = (L & 7) * (nwg >> 3) + (L >> 3);                            \
    const int r0 = (T & 15) * 128, c0 = (T >> 4) * 64;

template<bool BF16OUT>
__global__ __launch_bounds__(256) void gemm_bf16(
    const unsigned short* __restrict__ A,   // [2048][K] bf16
    const unsigned short* __restrict__ Bt,  // [>=nx*64][K] bf16
    void* __restrict__ Cv, int N, int K, int ldc, float oscale)
{
    __shared__ __align__(16) unsigned short As[2][128 * 64];
    __shared__ __align__(16) unsigned short Bs[2][64 * 64];
    const int tid = threadIdx.x;
    const int lane = tid & 63, wid = tid >> 6;
    const int wr = wid >> 1, wc = wid & 1;
    const int lrow = lane & 15, lkg = lane >> 4;
    XCD_REMAP()

    f32x4 acc[4][2];
    #pragma unroll
    for (int m = 0; m < 4; ++m)
        #pragma unroll
        for (int n = 0; n < 2; ++n) acc[m][n] = (f32x4)0.f;

    GEMM_BODY64()

    // D layout: col = lane&15, row = (lane>>4)*4 + j
    #pragma unroll
    for (int m = 0; m < 4; ++m) {
        int grow = r0 + wr * 64 + m * 16 + lkg * 4;
        #pragma unroll
        for (int n = 0; n < 2; ++n) {
            int gcol = c0 + wc * 32 + n * 16 + lrow;
            if (gcol < N) {
                #pragma unroll
                for (int j = 0; j < 4; ++j) {
                    float v = acc[m][n][j] * oscale;
                    if (BF16OUT)
                        ((unsigned short*)Cv)[(size_t)(grow + j) * ldc + gcol] = f2bf(v);
                    else
                        ((float*)Cv)[(size_t)(grow + j) * ldc + gcol] = v;
                }
            }
        }
    }
}

// ==== G4 special: kvb GEMM (N=4096, K=512) writing Kc / Vtc caches directly ====
__global__ __launch_bounds__(256) void gemm_kv(
    const unsigned short* __restrict__ A,   // kv_cb [2048][512]
    const unsigned short* __restrict__ Bt,  // wbuf  [4096][512]
    unsigned short* __restrict__ Kc,        // [16][2048][192]
    unsigned short* __restrict__ Vtc)       // [16][128][2048]
{
    __shared__ __align__(16) unsigned short As[2][128 * 64];
    __shared__ __align__(16) unsigned short Bs[2][64 * 64];
    const int tid = threadIdx.x;
    const int lane = tid & 63, wid = tid >> 6;
    const int wr = wid >> 1, wc = wid & 1;
    const int lrow = lane & 15, lkg = lane >> 4;
    const int K = 512;
    XCD_REMAP()

    f32x4 acc[4][2];
    #pragma unroll
    for (int m = 0; m < 4; ++m)
        #pragma unroll
        for (int n = 0; n < 2; ++n) acc[m][n] = (f32x4)0.f;

    GEMM_BODY64()

    #pragma unroll
    for (int m = 0; m < 4; ++m) {
        int grow = r0 + wr * 64 + m * 16 + lkg * 4;   // t base (mult of 4)
        #pragma unroll
        for (int n = 0; n < 2; ++n) {
            int gcol = c0 + wc * 32 + n * 16 + lrow;
            int head = gcol >> 8, c = gcol & 255;
            if (c < 128) {
                #pragma unroll
                for (int j = 0; j < 4; ++j)
                    Kc[((size_t)head * 2048 + grow + j) * 192 + c] = f2bf(acc[m][n][j]);
            } else {
                ushort4 o;
                o.x = f2bf(acc[m][n][0]); o.y = f2bf(acc[m][n][1]);
                o.z = f2bf(acc[m][n][2]); o.w = f2bf(acc[m][n][3]);
                *(ushort4*)(Vtc + ((size_t)head * 128 + (c - 128)) * 2048 + grow) = o;
            }
        }
    }
}

// ---- fused row kernel on qkv_c [2048][2112] ----
__global__ __launch_bounds__(256) void rms_kv(const float* __restrict__ qkv,
    const float* __restrict__ gq, const float* __restrict__ gkv,
    const int* __restrict__ positions, unsigned short* __restrict__ q_cb,
    unsigned short* __restrict__ kv_cb, float* __restrict__ kpe)
{
    __shared__ float sred[4];
    int row = blockIdx.x, tid = threadIdx.x;
    const float* p = qkv + (size_t)row * 2112;

    float ss = 0.f;
    for (int i = tid; i < 1536; i += 256) { float v = p[i]; ss += v * v; }
    ss = block_reduce(ss, false, sred);
    float sc = rsqrtf(ss / 1536.0f + EPS_);
    for (int i = tid; i < 1536; i += 256)
        q_cb[(size_t)row * 1536 + i] = f2bf(p[i] * sc * gq[i]);

    float s2 = 0.f;
    for (int i = tid; i < 512; i += 256) { float v = p[1536 + i]; s2 += v * v; }
    s2 = block_reduce(s2, false, sred);
    float sc2 = rsqrtf(s2 / 512.0f + EPS_);
    for (int i = tid; i < 512; i += 256)
        kv_cb[(size_t)row * 512 + i] = f2bf(p[1536 + i] * sc2 * gkv[i]);

    if (tid < 32) {
        int i = tid;
        float pos = (float)positions[row];
        float inv = powf(THETA_, -(float)i / 32.0f);
        float ang = pos * inv;
        float c = cosf(ang), s = sinf(ang);
        float x1 = p[2048 + i], x2 = p[2080 + i];
        kpe[(size_t)row * 64 + i]      = x1 * c - x2 * s;
        kpe[(size_t)row * 64 + 32 + i] = x2 * c + x1 * s;
    }
}

// ---- broadcast roped k_pe into all 16 heads' Kc[..][128:192] ----
__global__ __launch_bounds__(256) void kpe_kc(const float* __restrict__ kpe,
    unsigned short* __restrict__ Kc)
{
    int t = blockIdx.x, tid = threadIdx.x;
    int n = tid >> 4, i4 = (tid & 15) * 4;
    float4 p = *(const float4*)(kpe + (size_t)t * 64 + i4);
    ushort4 o; o.x = f2bf(p.x); o.y = f2bf(p.y); o.z = f2bf(p.z); o.w = f2bf(p.w);
    *(ushort4*)(Kc + ((size_t)n * 2048 + t) * 192 + 128 + i4) = o;
}

// ---- in-place RoPE fixup on qb bf16 (cols 128..191 per head); scale already in ----
__global__ __launch_bounds__(256) void rope_fix(unsigned short* __restrict__ qb,
    const int* __restrict__ positions)
{
    int t = blockIdx.x, tid = threadIdx.x;
    int n = tid >> 4;                 // head 0..15
    int i0 = (tid & 15) * 2;          // pair base 0..30
    float pos = (float)positions[t];
    unsigned short* p = qb + ((size_t)t * 16 + n) * 192 + 128;
    #pragma unroll
    for (int e = 0; e < 2; ++e) {
        int i = i0 + e;
        float inv = powf(THETA_, -(float)i / 32.0f);
        float ang = pos * inv;
        float c = cosf(ang), s = sinf(ang);
        float x1 = bf2f(p[i]), x2 = bf2f(p[32 + i]);
        p[i]      = f2bf(x1 * c - x2 * s);
        p[32 + i] = f2bf(x2 * c + x1 * s);
    }
}

// ==== MFMA flash attention, NCH=3 KV-split, swapped-QK^T, exp2 domain ====
#define QBLK  64
#define KVBLK 64
#define NCH   3

__global__ __launch_bounds__(256) void attn_part(
    const unsigned short* __restrict__ qb,    // [T][16][192] bf16 (scale*log2e folded)
    const unsigned short* __restrict__ Kc,    // [16][T][192] bf16
    const unsigned short* __restrict__ Vtc,   // [16][128][T] bf16
    unsigned short* __restrict__ Opart,       // [1536][64][128] bf16 unnormalized
    float2* __restrict__ Ml)                  // [1536][64] (m, l) — m in log2 units
{
    __shared__ __align__(16) unsigned short Ks[KVBLK * 192];   // 24 KB
    __shared__ __align__(16) unsigned short Vt[128 * KVBLK];   // 16 KB
    __shared__ __align__(16) unsigned short Ps[4][16 * KVBLK]; //  8 KB (48 total)

    const int bid = blockIdx.x;               // 0..1535
    const int xcd = bid & 7;
    const int j   = bid >> 3;                 // 0..191
    const int n   = xcd * 2 + (j >= 96);
    const int jj  = (j >= 96) ? j - 96 : j;   // 0..95
    const int qt  = 31 - (jj / NCH);
    const int ch  = jj % NCH;

    const int nt  = qt + 1;
    const int csz = (nt + NCH - 1) / NCH;
    const int tstart = ch * csz;
    if (tstart >= nt) return;
    const int tend = min(tstart + csz, nt);

    const int tid = threadIdx.x;
    const int lane = tid & 63, wid = tid >> 6;
    const int lrow = lane & 15;
    const int lkg  = lane >> 4;
    const int q0 = qt * QBLK;
    const int qrow_g = q0 + wid * 16 + lrow;
    const int pidx = ((n * 32 + qt) * NCH + ch);

    const unsigned short* Kh = Kc  + (size_t)n * 2048 * 192;
    const unsigned short* Vh = Vtc + (size_t)n * 128 * 2048;

    int koff[6], voff[4];
    #pragma unroll
    for (int p = 0; p < 6; ++p) {
        int u = p * 256 + tid;
        int row = u / 24, c8 = u % 24;
        koff[p] = row * 192 + ((c8 ^ (row & 7)) << 3);
    }
    #pragma unroll
    for (int p = 0; p < 4; ++p) {
        int u = p * 256 + tid;
        int dv = u >> 3, c8 = u & 7;
        voff[p] = dv * 2048 + ((c8 ^ (dv & 7)) << 3);
    }

    short8v qf[6];
    {
        const unsigned short* qrow = qb + ((size_t)qrow_g * 16 + n) * 192;
        #pragma unroll
        for (int ds = 0; ds < 6; ++ds)
            qf[ds] = *(const short8v*)(qrow + ds * 32 + lkg * 8);
    }

    f32x4 oacc[8];
    #pragma unroll
    for (int i = 0; i < 8; ++i) oacc[i] = (f32x4)0.f;
    float mrow = -3e38f;
    float lsum = 0.f;

    #pragma unroll
    for (int p = 0; p < 6; ++p)
        gload16(Kh + (size_t)tstart * KVBLK * 192 + koff[p], Ks + (p * 256 + wid * 64) * 8);
    #pragma unroll
    for (int p = 0; p < 4; ++p)
        gload16(Vh + tstart * KVBLK + voff[p], Vt + (p * 256 + wid * 64) * 8);

    for (int tile = tstart; tile < tend; ++tile) {
        const int s0 = tile * KVBLK;
        const bool more = (tile + 1 < tend);

        asm volatile("s_waitcnt vmcnt(4)" ::: "memory");   // K[t] landed
        __builtin_amdgcn_s_barrier();

        f32x4 sacc[4];
        #pragma unroll
        for (int ct = 0; ct < 4; ++ct) sacc[ct] = (f32x4)0.f;
        __builtin_amdgcn_s_setprio(1);
        #pragma unroll
        for (int ds = 0; ds < 6; ++ds) {
            #pragma unroll
            for (int ct = 0; ct < 4; ++ct) {
                int krow = ct * 16 + lrow;
                int byte = (krow * 384 + ds * 64 + lkg * 16) ^ ((krow & 7) << 4);
                short8v kf = *(const short8v*)((char*)Ks + byte);
                sacc[ct] = __builtin_amdgcn_mfma_f32_16x16x32_bf16(kf, qf[ds], sacc[ct], 0, 0, 0);
            }
        }
        __builtin_amdgcn_s_setprio(0);

        #pragma unroll
        for (int ct = 0; ct < 4; ++ct) {
            #pragma unroll
            for (int jq = 0; jq < 4; ++jq) {
                int key = s0 + ct * 16 + lkg * 4 + jq;
                if (key > qrow_g) sacc[ct][jq] = -3e38f;
            }
        }

        // ---- in-lane softmax (log2 domain) ----
        float tm = -3e38f;
        #pragma unroll
        for (int ct = 0; ct < 4; ++ct) {
            float a = fmaxf(sacc[ct][0], sacc[ct][1]);
            float b = fmaxf(sacc[ct][2], sacc[ct][3]);
            tm = fmaxf(tm, fmaxf(a, b));
        }
        tm = fmaxf(tm, __shfl_xor(tm, 16, 64));
        tm = fmaxf(tm, __shfl_xor(tm, 32, 64));

        const bool grow = !__all(tm <= mrow);   // defer-max
        float corr = 1.f;
        if (grow) {
            float mn = fmaxf(mrow, tm);
            corr = exp2f(mrow - mn);
            mrow = mn;
        }

        float psum = 0.f;
        unsigned short pb[4][4];
        #pragma unroll
        for (int ct = 0; ct < 4; ++ct)
            #pragma unroll
            for (int jq = 0; jq < 4; ++jq) {
                float sv = sacc[ct][jq];
                float p = (sv > -1e37f) ? exp2f(sv - mrow) : 0.f;
                psum += p;
                pb[ct][jq] = f2bf(p);
            }
        psum += __shfl_xor(psum, 16, 64);
        psum += __shfl_xor(psum, 32, 64);
        lsum = grow ? (lsum * corr + psum) : (lsum + psum);

        if (grow) {
            float corr4[4];
            #pragma unroll
            for (int jq = 0; jq < 4; ++jq)
                corr4[jq] = __shfl(corr, (lane & 48) | (lkg * 4 + jq), 64);
            #pragma unroll
            for (int dt = 0; dt < 8; ++dt)
                #pragma unroll
                for (int jq = 0; jq < 4; ++jq) oacc[dt][jq] *= corr4[jq];
        }

        #pragma unroll
        for (int ct = 0; ct < 4; ++ct) {
            int c0k = ct * 16 + lkg * 4;
            int byte = ((lrow * 64 + c0k) * 2) ^ ((lrow & 7) << 4);
            uint2 w;
            w.x = (unsigned)pb[ct][0] | ((unsigned)pb[ct][1] << 16);
            w.y = (unsigned)pb[ct][2] | ((unsigned)pb[ct][3] << 16);
            *(uint2*)((char*)Ps[wid] + byte) = w;
        }

        asm volatile("s_waitcnt vmcnt(0)" ::: "memory");   // V[t] landed
        __builtin_amdgcn_s_barrier();

        __builtin_amdgcn_s_setprio(1);
        #pragma unroll
        for (int ks = 0; ks < 2; ++ks) {
            int abyte = ((lrow * 64 + ks * 32 + lkg * 8) * 2) ^ ((lrow & 7) << 4);
            short8v af = *(const short8v*)((char*)Ps[wid] + abyte);
            #pragma unroll
            for (int dt = 0; dt < 8; ++dt) {
                int vrow = dt * 16 + lrow;
                int byte = ((vrow * 128 + ks * 64 + lkg * 16)) ^ ((vrow & 7) << 4);
                short8v bf = *(const short8v*)((char*)Vt + byte);
                oacc[dt] = __builtin_amdgcn_mfma_f32_16x16x32_bf16(af, bf, oacc[dt], 0, 0, 0);
            }
        }
        __builtin_amdgcn_s_setprio(0);

        __builtin_amdgcn_s_barrier();
        if (more) {
            const int s1 = s0 + KVBLK;
            #pragma unroll
            for (int p = 0; p < 6; ++p)
                gload16(Kh + (size_t)s1 * 192 + koff[p], Ks + (p * 256 + wid * 64) * 8);
            #pragma unroll
            for (int p = 0; p < 4; ++p)
                gload16(Vh + s1 + voff[p], Vt + (p * 256 + wid * 64) * 8);
        }
    }

    #pragma unroll
    for (int dt = 0; dt < 8; ++dt)
        #pragma unroll
        for (int jq = 0; jq < 4; ++jq) {
            int row = wid * 16 + lkg * 4 + jq;
            Opart[(size_t)pidx * 8192 + row * 128 + dt * 16 + lrow] = f2bf(oacc[dt][jq]);
        }
    if (lkg == 0)
        Ml[(size_t)pidx * 64 + wid * 16 + lrow] = make_float2(mrow, lsum);
}

// -------- combine <=3 partials per (head, qtile); weights in exp2 domain --------
__global__ __launch_bounds__(256) void attn_combine(
    const unsigned short* __restrict__ Opart, const float2* __restrict__ Ml,
    unsigned short* __restrict__ aob)
{
    const int bid = blockIdx.x;               // 512 = head*32 + qt
    const int head = bid >> 5, qt = bid & 31;
    const int nt = qt + 1, csz = (nt + NCH - 1) / NCH;
    const int nch = (nt + csz - 1) / csz;
    const int tid = threadIdx.x;
    const int r = tid >> 2, qc = tid & 3;
    const int base = (head * 32 + qt) * NCH;

    float mi[NCH], li[NCH];
    float m = -3e38f;
    #pragma unroll
    for (int i = 0; i < NCH; ++i) {
        mi[i] = -3e38f; li[i] = 0.f;
        if (i < nch) {
            float2 v = Ml[(size_t)(base + i) * 64 + r];
            mi[i] = v.x; li[i] = v.y;
            m = fmaxf(m, v.x);
        }
    }
    float acc[32];
    #pragma unroll
    for (int u = 0; u < 32; ++u) acc[u] = 0.f;
    float l = 0.f;
    #pragma unroll
    for (int i = 0; i < NCH; ++i) {
        if (i < nch) {
            float w = exp2f(mi[i] - m);
            l += w * li[i];
            const unsigned short* op = Opart + (size_t)(base + i) * 8192 + r * 128 + qc * 32;
            #pragma unroll
            for (int u = 0; u < 4; ++u) {
                short8v v8 = *(const short8v*)(op + u * 8);
                #pragma unroll
                for (int e = 0; e < 8; ++e)
                    acc[u * 8 + e] += w * bf2f((unsigned short)v8[e]);
            }
        }
    }
    float invl = 1.0f / l;
    unsigned short* dst = aob + (size_t)(qt * 64 + r) * 2048 + head * 128 + qc * 32;
    #pragma unroll
    for (int u = 0; u < 4; ++u) {
        short8v o8;
        #pragma unroll
        for (int e = 0; e < 8; ++e) o8[e] = (short)f2bf(acc[u * 8 + e] * invl);
        *(short8v*)(dst + u * 8) = o8;
    }
}

extern "C" void kernel_launch(void* const* d_in, const int* in_sizes, int n_in,
                              void* d_out, int out_size, void* d_ws, size_t ws_size,
                              hipStream_t stream)
{
    const float* x         = (const float*)d_in[0];
    const int*   positions = (const int*)  d_in[1];
    const float* w_q_a     = (const float*)d_in[2];
    const float* q_a_norm  = (const float*)d_in[3];
    const float* w_q_b     = (const float*)d_in[4];
    const float* w_kv_a    = (const float*)d_in[5];
    const float* kv_a_norm = (const float*)d_in[6];
    const float* w_kv_b    = (const float*)d_in[7];
    const float* w_o       = (const float*)d_in[8];
    float* out = (float*)d_out;

    // softmax scale * log2(e), folded into G2's epilogue
    const float QSCALE = 0.07216878364870323f * 1.4426950408889634f;

    // ---- workspace layout (~77.6 MB) ----
    // D0 union (35.66 MB): [qkv_c fp32 | q_cb | kv_cb | kpe | wbuf] all dead
    // before attn_part; Opart (25.17 MB) + Ml (0.79 MB) alias the region.
    // G5's wt_bf16 refills wbuf only AFTER attn_combine (Opart/Ml dead).
    char* base = (char*)d_ws;
    char* D0 = base;
    float* qkv_c = (float*)D0;                                     // 2048*2112*4 = 17.30 MB
    unsigned short* q_cb  = (unsigned short*)(D0 + 17301504);      // 2048*1536*2 =  6.29 MB
    unsigned short* kv_cb = (unsigned short*)(D0 + 23592960);      // 2048*512*2  =  2.10 MB
    float* kpe            = (float*)(D0 + 25690112);               // 2048*64*4   =  0.52 MB
    unsigned short* wbuf  = (unsigned short*)(D0 + 26214400);      // up to 9.44 MB
    unsigned short* Opart = (unsigned short*)D0;                   // 1536*8192*2 = 25.17 MB
    float2* Ml            = (float2*)(D0 + 25165824);              // 1536*64*8   =  0.79 MB
    char* D1 = D0 + 35651584;
    unsigned short* Kc  = (unsigned short*)D1;                     // 16*2048*192 = 12.58 MB
    unsigned short* Vtc = Kc + (size_t)16 * 2048 * 192;            // 16*128*2048 =  8.39 MB
    char* D2 = D1 + (size_t)(12582912 + 8388608);
    unsigned short* xb  = (unsigned short*)D2;                     // 2048*2048*2 =  8.39 MB
    unsigned short* aob = xb;                                      // alias (xb dead after G13)
    char* D3 = D2 + 8388608;
    unsigned short* qb = (unsigned short*)D3;                      // 2048*16*192*2 = 12.58 MB

    dim3 blk(256);

    conv_bf16<<<(2048 * 2048 / 4 + 255) / 256, blk, 0, stream>>>(x, xb, 2048 * 2048 / 4);

    // G13: qkv_c = x @ [w_q_a | w_kv_a]  (N=2112, K=2048) fp32 out; 528 blocks
    wt_bf16<<<dim3(1536 / 32, 2048 / 32), blk, 0, stream>>>(w_q_a, wbuf, 2048, 1536);
    wt_bf16<<<dim3(576 / 32, 2048 / 32), blk, 0, stream>>>(w_kv_a, wbuf + (size_t)1536 * 2048, 2048, 576);
    gemm_bf16<false><<<528, blk, 0, stream>>>(xb, wbuf, qkv_c, 2112, 2048, 2112, 1.0f);
    rms_kv<<<2048, blk, 0, stream>>>(qkv_c, q_a_norm, kv_a_norm, positions, q_cb, kv_cb, kpe);

    // G2: qb = (q_cb @ w_q_b) * QSCALE, bf16 direct; 768 blocks
    wt_bf16<<<dim3(3072 / 32, 1536 / 32), blk, 0, stream>>>(w_q_b, wbuf, 1536, 3072);
    gemm_bf16<true><<<768, blk, 0, stream>>>(q_cb, wbuf, qb, 3072, 1536, 3072, QSCALE);
    rope_fix<<<2048, blk, 0, stream>>>(qb, positions);

    kpe_kc<<<2048, blk, 0, stream>>>(kpe, Kc);

    // G4: (kv_cb @ w_kv_b) -> Kc / Vtc directly; 1024 blocks
    wt_bf16<<<dim3(4096 / 32, 512 / 32), blk, 0, stream>>>(w_kv_b, wbuf, 512, 4096);
    gemm_kv<<<1024, blk, 0, stream>>>(kv_cb, wbuf, Kc, Vtc);

    // attention: 1536 NCH=3 KV-split jobs + combine
    attn_part<<<1536, blk, 0, stream>>>(qb, Kc, Vtc, Opart, Ml);
    attn_combine<<<512, blk, 0, stream>>>(Opart, Ml, aob);

    // G5: out = aob @ w_o   (N=2048, K=2048) fp32 out; 512 blocks
    wt_bf16<<<dim3(2048 / 32, 2048 / 32), blk, 0, stream>>>(w_o, wbuf, 2048, 2048);
    gemm_bf16<false><<<512, blk, 0, stream>>>(aob, wbuf, out, 2048, 2048, 2048, 1.0f);
}